// Round 1
// baseline (226.481 us; speedup 1.0000x reference)
//
#include <hip/hip_runtime.h>
#include <math.h>

#define RANK 33
#define D 32            // rank-1 (space dims)
#define N_ENT 50000
#define N_REL 500
#define NQ 2000
#define M_TILE 500

__device__ __forceinline__ float waveReduceSum(float v) {
    #pragma unroll
    for (int off = 32; off > 0; off >>= 1)
        v += __shfl_xor(v, off, 64);
    return v;
}

// ---------------- K1: expmap0 for all entities. One wave (64 lanes) per row.
__global__ void k_expmap(const float* __restrict__ ent, float* __restrict__ emb) {
    int wave = (blockIdx.x * blockDim.x + threadIdx.x) >> 6;
    int lane = threadIdx.x & 63;
    if (wave >= N_ENT) return;
    const float* u = ent + (long)wave * RANK;
    float uv = (lane < RANK) ? u[lane] : 0.0f;
    // clip to MAX_NORM=2
    float en = sqrtf(waveReduceSum(uv * uv));
    float scale = fminf(1.0f, 2.0f / fmaxf(en, 1e-12f));
    uv *= scale;
    // inner = -u0^2 + sum_{i>=1} u_i^2
    float sp2 = waveReduceSum((lane >= 1 && lane < RANK) ? uv * uv : 0.0f);
    float u0 = __shfl(uv, 0, 64);
    float inner = sp2 - u0 * u0;
    float nomin = sqrtf(fmaxf(inner, 1e-8f));
    float s = sinhf(nomin) / nomin;
    // space_i = s*u_i (i>=1); time = sqrt(1 + sum space^2)
    float sv = s * uv;
    float t2 = waveReduceSum((lane >= 1 && lane < RANK) ? sv * sv : 0.0f);
    float* o = emb + (long)wave * RANK;
    if (lane == 0) o[0] = sqrtf(1.0f + t2);
    if (lane >= 1 && lane < RANK) o[lane] = sv;
}

// ---------------- K2: per-query transform. One wave per query; lane i<32 owns space dim i.
__global__ void k_query(const float* __restrict__ emb,
                        const float* __restrict__ rot_raw,
                        const float* __restrict__ boosts,
                        const int* __restrict__ queries,
                        float* __restrict__ lhs_neg) {
    int wave = (blockIdx.x * blockDim.x + threadIdx.x) >> 6;
    int lane = threadIdx.x & 63;
    if (wave >= NQ) return;
    int h = queries[wave * 3 + 0];
    int r = queries[wave * 3 + 1];
    const float* eh = emb + (long)h * RANK;
    float lhs_t = eh[0];
    float x = (lane < D) ? eh[1 + lane] : 0.0f;
    // Apply Householder reflections sequentially: x <- H_k x, k = 1..32.
    // (x^T P = x^T H_1..H_32 = (H_32..H_1 x)^T since each H_k symmetric.)
    const float* rr = rot_raw + (long)r * D * D;
    for (int k = 0; k < D; ++k) {
        float g = 0.0f;
        if (lane < D) {
            float w = rr[k * D + lane];
            g = 0.5f * w * (1.0f + erff(w * 0.70710678118654752f)); // exact gelu
        }
        float dvx = waveReduceSum(g * x);
        float n   = waveReduceSum(g * g);
        x -= (2.0f * dvx / n) * g;
    }
    // Lorentz boost
    float b = 0.0f;
    if (lane < D) b = tanhf(boosts[(long)r * D + lane]) * (1.0f / 33.0f);
    float b2   = waveReduceSum(b * b);
    float bdot = waveReduceSum(b * x);
    float zeta = 1.0f / (sqrtf(1.0f - b2) + 1e-8f);
    float x0 = zeta * lhs_t - zeta * bdot;
    float xr = -zeta * lhs_t * b + x + (zeta - 1.0f) / (b2 + 1e-9f) * b * bdot;
    float* o = lhs_neg + (long)wave * RANK;
    if (lane == 0) o[0] = -x0;           // lhs_neg negates the time component
    if (lane < D) o[1 + lane] = xr;
}

// ---------------- K3: scores = 2 - 2 * lhs_neg @ emb^T.  (2000 x 50000, fp32)
// One thread per entity column n; emb row n held in 33 VGPRs; lhs loads are
// wave-uniform (scalar). Stores coalesced across the wave for each m.
__global__ void k_scores(const float* __restrict__ lhs_neg,
                         const float* __restrict__ emb,
                         float* __restrict__ out) {
    int n = blockIdx.x * blockDim.x + threadIdx.x;
    if (n >= N_ENT) return;
    int m0 = blockIdx.y * M_TILE;
    float e[RANK];
    #pragma unroll
    for (int k = 0; k < RANK; ++k) e[k] = emb[(long)n * RANK + k];
    for (int m = m0; m < m0 + M_TILE; ++m) {
        const float* l = lhs_neg + m * RANK;
        float acc = 0.0f;
        #pragma unroll
        for (int k = 0; k < RANK; ++k) acc = fmaf(l[k], e[k], acc);
        out[(size_t)m * N_ENT + n] = 2.0f - 2.0f * acc;
    }
}

// ---------------- K4a: per-relation norms (raw rot Frobenius + boost L2).
__global__ void k_norms(const float* __restrict__ rot_raw,
                        const float* __restrict__ boosts,
                        float* __restrict__ rotF, float* __restrict__ boostN) {
    int wave = (blockIdx.x * blockDim.x + threadIdx.x) >> 6;
    int lane = threadIdx.x & 63;
    if (wave >= N_REL) return;
    const float* rr = rot_raw + (long)wave * (D * D);
    float s = 0.0f;
    #pragma unroll
    for (int i = 0; i < (D * D) / 64; ++i) {
        float w = rr[i * 64 + lane];
        s += w * w;
    }
    s = waveReduceSum(s);
    float sb = 0.0f;
    if (lane < D) { float w = boosts[(long)wave * D + lane]; sb = w * w; }
    sb = waveReduceSum(sb);
    if (lane == 0) { rotF[wave] = sqrtf(s); boostN[wave] = sqrtf(sb); }
}

// ---------------- K4b: reg[i,j] = rotF[j] + boostN[i]  (500 x 500 broadcast)
__global__ void k_reg(const float* __restrict__ rotF, const float* __restrict__ boostN,
                      float* __restrict__ out) {
    int idx = blockIdx.x * blockDim.x + threadIdx.x;
    if (idx >= N_REL * N_REL) return;
    int i = idx / N_REL;
    int j = idx - i * N_REL;
    out[idx] = rotF[j] + boostN[i];
}

extern "C" void kernel_launch(void* const* d_in, const int* in_sizes, int n_in,
                              void* d_out, int out_size, void* d_ws, size_t ws_size,
                              hipStream_t stream) {
    const float* ent     = (const float*)d_in[0];   // 50000 x 33
    const float* rot     = (const float*)d_in[1];   // 500 x 32 x 32
    const float* boosts  = (const float*)d_in[2];   // 500 x 32
    const int*   queries = (const int*)d_in[3];     // 2000 x 3 (h, r, t)
    float* out = (float*)d_out;                     // scores (2000x50000) ++ reg (500x500)

    float* ws     = (float*)d_ws;
    float* emb    = ws;                  // 1,650,000 floats
    float* lhs    = ws + 1650000;        //    66,000 floats
    float* rotF   = ws + 1716000;        //       500 floats
    float* boostN = ws + 1716500;        //       500 floats

    // K1: 50000 waves, 4 waves/block
    hipLaunchKernelGGL(k_expmap, dim3((N_ENT + 3) / 4), dim3(256), 0, stream, ent, emb);
    // K2: 2000 waves
    hipLaunchKernelGGL(k_query, dim3(NQ / 4), dim3(256), 0, stream,
                       emb, rot, boosts, queries, lhs);
    // K3: scores GEMM — grid (ceil(50000/256), 2000/M_TILE)
    hipLaunchKernelGGL(k_scores, dim3((N_ENT + 255) / 256, NQ / M_TILE), dim3(256), 0, stream,
                       lhs, emb, out);
    // K4a: 500 waves
    hipLaunchKernelGGL(k_norms, dim3((N_REL + 3) / 4), dim3(256), 0, stream,
                       rot, boosts, rotF, boostN);
    // K4b: 250000 elements
    hipLaunchKernelGGL(k_reg, dim3((N_REL * N_REL + 255) / 256), dim3(256), 0, stream,
                       rotF, boostN, out + (size_t)NQ * N_ENT);
}

// Round 2
// 147.098 us; speedup vs baseline: 1.5397x; 1.5397x over previous
//
#include <hip/hip_runtime.h>
#include <math.h>

#define RANK 33
#define D 32            // rank-1 (space dims)
#define N_ENT 50000
#define N_REL 500
#define NQ 2000
#define W_PAD 50176     // emb_T row stride (98 * 512)
#define NQ_PAD 2048     // lhs_T row stride
#define MT 100          // m per y-block in k_scores (grid y = 20)

typedef float f2v __attribute__((ext_vector_type(2)));

__device__ __forceinline__ float waveReduceSum(float v) {
    #pragma unroll
    for (int off = 32; off > 0; off >>= 1)
        v += __shfl_xor(v, off, 64);
    return v;
}

// ---------------- K1: expmap0 for all entities -> emb_T[33][W_PAD] (dim-major).
__global__ void k_expmap(const float* __restrict__ ent, float* __restrict__ embT) {
    int wave = (blockIdx.x * blockDim.x + threadIdx.x) >> 6;
    int lane = threadIdx.x & 63;
    if (wave >= N_ENT) return;
    const float* u = ent + (long)wave * RANK;
    float uv = (lane < RANK) ? u[lane] : 0.0f;
    float en = sqrtf(waveReduceSum(uv * uv));
    float scale = fminf(1.0f, 2.0f / fmaxf(en, 1e-12f));
    uv *= scale;
    float sp2 = waveReduceSum((lane >= 1 && lane < RANK) ? uv * uv : 0.0f);
    float u0 = __shfl(uv, 0, 64);
    float inner = sp2 - u0 * u0;
    float nomin = sqrtf(fmaxf(inner, 1e-8f));
    float s = sinhf(nomin) / nomin;
    float sv = s * uv;
    float t2 = waveReduceSum((lane >= 1 && lane < RANK) ? sv * sv : 0.0f);
    if (lane == 0) embT[wave] = sqrtf(1.0f + t2);                       // time row
    if (lane >= 1 && lane < RANK) embT[(size_t)lane * W_PAD + wave] = sv;
}

// ---------------- K2: per-query transform -> lhs_T[33][NQ_PAD]. One wave per query.
__global__ void k_query(const float* __restrict__ embT,
                        const float* __restrict__ rot_raw,
                        const float* __restrict__ boosts,
                        const int* __restrict__ queries,
                        float* __restrict__ lhsT) {
    int wave = (blockIdx.x * blockDim.x + threadIdx.x) >> 6;
    int lane = threadIdx.x & 63;
    if (wave >= NQ) return;
    int h = queries[wave * 3 + 0];
    int r = queries[wave * 3 + 1];
    float lhs_t = embT[h];
    float x = (lane < D) ? embT[(size_t)(1 + lane) * W_PAD + h] : 0.0f;
    // x^T (H_0 H_1 .. H_31) = H_31(..H_1(H_0 x)..)  (each H_k symmetric)
    const float* rr = rot_raw + (long)r * D * D;
    for (int k = 0; k < D; ++k) {
        float g = 0.0f;
        if (lane < D) {
            float w = rr[k * D + lane];
            g = 0.5f * w * (1.0f + erff(w * 0.70710678118654752f)); // exact gelu
        }
        float dvx = waveReduceSum(g * x);
        float n   = waveReduceSum(g * g);
        x -= (2.0f * dvx / n) * g;
    }
    float b = 0.0f;
    if (lane < D) b = tanhf(boosts[(long)r * D + lane]) * (1.0f / 33.0f);
    float b2   = waveReduceSum(b * b);
    float bdot = waveReduceSum(b * x);
    float zeta = 1.0f / (sqrtf(1.0f - b2) + 1e-8f);
    float x0 = zeta * lhs_t - zeta * bdot;
    float xr = -zeta * lhs_t * b + x + (zeta - 1.0f) / (b2 + 1e-9f) * b * bdot;
    if (lane < D) lhsT[(size_t)(1 + lane) * NQ_PAD + wave] = xr;
    if (lane == 0) lhsT[wave] = -x0;     // negated time component
}

// ---------------- K3: scores = 2 - 2 * lhs_neg @ emb^T  (2000 x 50000 fp32)
// Register-blocked: thread owns 2 adjacent n (float2 e-loads/stores) x 4 m
// per tile (one uniform float4 l-load per k feeds 8 FMAs).
__global__ void k_scores(const float* __restrict__ lhsT,
                         const float* __restrict__ embT,
                         float* __restrict__ out) {
    int t = threadIdx.x;
    int n = blockIdx.x * 512 + t * 2;
    if (n >= N_ENT) return;
    int m0 = blockIdx.y * MT;
    f2v e[RANK];
    #pragma unroll
    for (int k = 0; k < RANK; ++k)
        e[k] = *(const f2v*)(embT + (size_t)k * W_PAD + n);
    for (int mt = m0; mt < m0 + MT; mt += 4) {
        float a0x = 0.f, a0y = 0.f, a1x = 0.f, a1y = 0.f;
        float a2x = 0.f, a2y = 0.f, a3x = 0.f, a3y = 0.f;
        #pragma unroll
        for (int k = 0; k < RANK; ++k) {
            float4 l = *(const float4*)(lhsT + k * NQ_PAD + mt);
            float ex = e[k].x, ey = e[k].y;
            a0x = fmaf(l.x, ex, a0x); a0y = fmaf(l.x, ey, a0y);
            a1x = fmaf(l.y, ex, a1x); a1y = fmaf(l.y, ey, a1y);
            a2x = fmaf(l.z, ex, a2x); a2y = fmaf(l.z, ey, a2y);
            a3x = fmaf(l.w, ex, a3x); a3y = fmaf(l.w, ey, a3y);
        }
        f2v s0 = {2.f - 2.f * a0x, 2.f - 2.f * a0y};
        f2v s1 = {2.f - 2.f * a1x, 2.f - 2.f * a1y};
        f2v s2 = {2.f - 2.f * a2x, 2.f - 2.f * a2y};
        f2v s3 = {2.f - 2.f * a3x, 2.f - 2.f * a3y};
        __builtin_nontemporal_store(s0, (f2v*)(out + (size_t)(mt + 0) * N_ENT + n));
        __builtin_nontemporal_store(s1, (f2v*)(out + (size_t)(mt + 1) * N_ENT + n));
        __builtin_nontemporal_store(s2, (f2v*)(out + (size_t)(mt + 2) * N_ENT + n));
        __builtin_nontemporal_store(s3, (f2v*)(out + (size_t)(mt + 3) * N_ENT + n));
    }
}

// ---------------- K4a: per-relation norms (raw rot Frobenius + boost L2).
__global__ void k_norms(const float* __restrict__ rot_raw,
                        const float* __restrict__ boosts,
                        float* __restrict__ rotF, float* __restrict__ boostN) {
    int wave = (blockIdx.x * blockDim.x + threadIdx.x) >> 6;
    int lane = threadIdx.x & 63;
    if (wave >= N_REL) return;
    const float* rr = rot_raw + (long)wave * (D * D);
    float s = 0.0f;
    #pragma unroll
    for (int i = 0; i < (D * D) / 64; ++i) {
        float w = rr[i * 64 + lane];
        s += w * w;
    }
    s = waveReduceSum(s);
    float sb = 0.0f;
    if (lane < D) { float w = boosts[(long)wave * D + lane]; sb = w * w; }
    sb = waveReduceSum(sb);
    if (lane == 0) { rotF[wave] = sqrtf(s); boostN[wave] = sqrtf(sb); }
}

// ---------------- K4b: reg[i,j] = rotF[j] + boostN[i]
__global__ void k_reg(const float* __restrict__ rotF, const float* __restrict__ boostN,
                      float* __restrict__ out) {
    int idx = blockIdx.x * blockDim.x + threadIdx.x;
    if (idx >= N_REL * N_REL) return;
    int i = idx / N_REL;
    int j = idx - i * N_REL;
    out[idx] = rotF[j] + boostN[i];
}

extern "C" void kernel_launch(void* const* d_in, const int* in_sizes, int n_in,
                              void* d_out, int out_size, void* d_ws, size_t ws_size,
                              hipStream_t stream) {
    const float* ent     = (const float*)d_in[0];   // 50000 x 33
    const float* rot     = (const float*)d_in[1];   // 500 x 32 x 32
    const float* boosts  = (const float*)d_in[2];   // 500 x 32
    const int*   queries = (const int*)d_in[3];     // 2000 x 3 (h, r, t)
    float* out = (float*)d_out;                     // scores (2000x50000) ++ reg (500x500)

    float* ws     = (float*)d_ws;
    float* embT   = ws;                               // 33 * 50176 = 1,655,808 floats
    float* lhsT   = ws + (size_t)RANK * W_PAD;        // 33 * 2048  =    67,584 floats
    float* rotF   = lhsT + (size_t)RANK * NQ_PAD;     //       500 floats
    float* boostN = rotF + N_REL;                     //       500 floats

    hipLaunchKernelGGL(k_expmap, dim3((N_ENT + 3) / 4), dim3(256), 0, stream, ent, embT);
    hipLaunchKernelGGL(k_query, dim3(NQ / 4), dim3(256), 0, stream,
                       embT, rot, boosts, queries, lhsT);
    hipLaunchKernelGGL(k_scores, dim3(98, NQ / MT), dim3(256), 0, stream,
                       lhsT, embT, out);
    hipLaunchKernelGGL(k_norms, dim3((N_REL + 3) / 4), dim3(256), 0, stream,
                       rot, boosts, rotF, boostN);
    hipLaunchKernelGGL(k_reg, dim3((N_REL * N_REL + 255) / 256), dim3(256), 0, stream,
                       rotF, boostN, out + (size_t)NQ * N_ENT);
}